// Round 8
// baseline (233.347 us; speedup 1.0000x reference)
//
#include <hip/hip_runtime.h>
#include <math.h>

// Problem constants (fixed by reference setup_inputs)
#define BB 128
#define LL 512
#define DD 256
#define TT 64
#define GG 8       // LL / TT
#define NQ (DD/4)  // 64 f32x4 per D-row

typedef float f32x4 __attribute__((ext_vector_type(4)));

__device__ __forceinline__ float sigm(float x) {
    return 1.0f / (1.0f + __expf(-x));
}
__device__ __forceinline__ f32x4 sigm4(f32x4 z) {
    f32x4 r;
    r.x = sigm(z.x); r.y = sigm(z.y); r.z = sigm(z.z); r.w = sigm(z.w);
    return r;
}

// ---------------- K1: summaries + last-block-per-batch gate compute ----------------
// grid = 1024 blocks (b, t8-chunk) x 256 threads. Wave w owns t-groups
// (t8*8 + 2w, +1). Emits rowMean[b,t], colpart[bk,d]; the 8th (last-done)
// block of each batch then computes h_att[b,*], w_att[b,*] (deterministic:
// values don't depend on which block runs the gate phase).
__global__ __launch_bounds__(256) void k_sum(
    const f32x4* __restrict__ aco4, const f32x4* __restrict__ vis4,
    float* __restrict__ rowMean,   // [BB*TT]
    float* __restrict__ colpart,   // [1024*DD]
    float* __restrict__ h_att,     // [BB*TT]
    float* __restrict__ w_att,     // [BB*DD]
    const float* __restrict__ Wh, const float* __restrict__ bh,
    const float* __restrict__ Ww, const float* __restrict__ bw,
    int* __restrict__ cnt)         // [BB], zeroed each launch
{
    const int tid  = threadIdx.x;
    const int w    = tid >> 6;
    const int lane = tid & 63;
    const int bk   = blockIdx.x;
    const int b    = bk >> 3;
    const int t8   = bk & 7;

    const size_t rowBase = (size_t)b * LL + (size_t)t8 * 64 + (size_t)w * 16;

    // hw = 0.5*(mean_a + mean_v) = (sum over 8 rows of (a+v)) / 16
    f32x4 hw0 = 0.f, hw1 = 0.f;
#pragma unroll
    for (int j = 0; j < 8; ++j)
        hw0 += aco4[(rowBase + j) * NQ + lane] + vis4[(rowBase + j) * NQ + lane];
#pragma unroll
    for (int j = 0; j < 8; ++j)
        hw1 += aco4[(rowBase + 8 + j) * NQ + lane] + vis4[(rowBase + 8 + j) * NQ + lane];
    hw0 *= 0.0625f;
    hw1 *= 0.0625f;

    // row means over D for the wave's two t-groups (64 lanes = 1 wave)
    float s0 = hw0.x + hw0.y + hw0.z + hw0.w;
    float s1 = hw1.x + hw1.y + hw1.z + hw1.w;
#pragma unroll
    for (int off = 32; off > 0; off >>= 1) {
        s0 += __shfl_xor(s0, off, 64);
        s1 += __shfl_xor(s1, off, 64);
    }
    if (lane == 0) {
        const int btBase = b * TT + t8 * 8 + 2 * w;
        rowMean[btBase]     = s0 * (1.0f / DD);
        rowMean[btBase + 1] = s1 * (1.0f / DD);
    }

    // per-block column partial (sum of hw over 8 t-groups, per d)
    __shared__ __align__(16) float red[4][DD];
    *reinterpret_cast<f32x4*>(&red[w][lane * 4]) = hw0 + hw1;
    __syncthreads();
    colpart[(size_t)bk * DD + tid] =
        red[0][tid] + red[1][tid] + red[2][tid] + red[3][tid];

    // ---- last-done block of this batch computes the gates ----
    __threadfence();            // release our rowMean/colpart writes (device scope)
    __syncthreads();
    __shared__ int isLast;
    if (tid == 0) {
        int old = atomicAdd(&cnt[b], 1);
        isLast = (old == 7);
        __threadfence();        // acquire: subsequent reads see peers' writes
    }
    __syncthreads();
    if (!isLast) return;

    __shared__ float rm[TT];
    __shared__ float cm[DD];
    {
        float cs = 0.f;
#pragma unroll
        for (int p = 0; p < 8; ++p)
            cs += colpart[(size_t)(b * 8 + p) * DD + tid];
        cm[tid] = cs * (1.0f / TT);
        if (tid < TT) rm[tid] = rowMean[b * TT + tid];
    }
    __syncthreads();

    if (tid < TT) {
        float acc = bh[tid];
#pragma unroll 8
        for (int j = 0; j < TT; ++j) acc += rm[j] * Wh[tid * TT + j];
        h_att[b * TT + tid] = sigm(acc);
    }
    {
        float acc = bw[tid];
        const f32x4* Wr = reinterpret_cast<const f32x4*>(Ww + (size_t)tid * DD);
#pragma unroll 8
        for (int kq = 0; kq < NQ; ++kq) {
            f32x4 wq = Wr[kq];
            acc += cm[4 * kq] * wq.x + cm[4 * kq + 1] * wq.y +
                   cm[4 * kq + 2] * wq.z + cm[4 * kq + 3] * wq.w;
        }
        w_att[b * DD + tid] = sigm(acc);
    }
}

// ---------------- K2: pool-recompute + apply (R5's proven version) ----------------
// grid = 8192 blocks (b, t) x 256 threads (r=tid>>6 in 0..3, q=tid&63).
// Thread owns rows (t*8 + r) and (t*8 + r + 4), one f32x4 column each.
// Pools its own 8-row group in LDS, recomputes c_att locally, applies
// scale, NT-stores both outputs.
__global__ __launch_bounds__(256) void k_apply(
    const f32x4* __restrict__ aco4, const f32x4* __restrict__ vis4,
    const int* __restrict__ isb,
    const float* __restrict__ h_att, const float* __restrict__ w_att,
    const float* __restrict__ cw, const float* __restrict__ cb,
    f32x4* __restrict__ out4)
{
    const int tid = threadIdx.x;
    const int r   = tid >> 6;
    const int q   = tid & 63;
    const int bk  = blockIdx.x;
    const int b   = bk >> 6;
    const int t   = bk & 63;

    const size_t row0 = (size_t)b * LL + (size_t)t * GG + r;  // rows r, r+4
    const size_t N4   = (size_t)BB * LL * NQ;

    const size_t i0 = row0 * NQ + q;
    const size_t i1 = (row0 + 4) * NQ + q;

    f32x4 a0 = aco4[i0], a1 = aco4[i1];
    f32x4 v0 = vis4[i0], v1 = vis4[i1];

    __shared__ __align__(16) f32x4 redA[4][64];
    __shared__ __align__(16) f32x4 redV[4][64];
    redA[r][q] = a0 + a1;
    redV[r][q] = v0 + v1;
    __syncthreads();

    const f32x4 pa = (redA[0][q] + redA[1][q] + redA[2][q] + redA[3][q]) * 0.125f;
    const f32x4 pv = (redV[0][q] + redV[1][q] + redV[2][q] + redV[3][q]) * 0.125f;

    const f32x4 c  = sigm4(cw[0] * pa + cw[1] * pv + cb[0]);
    const float h  = h_att[b * TT + t];
    const f32x4 w4 = *reinterpret_cast<const f32x4*>(w_att + (size_t)b * DD + q * 4);
    const f32x4 sc = (h + w4 + c) * (1.0f / 3.0f);

    const int m0 = isb[row0];
    const int m1 = isb[row0 + 4];
    if (m0 == 1) { a0 *= sc; v0 *= sc; }
    if (m1 == 1) { a1 *= sc; v1 *= sc; }

    __builtin_nontemporal_store(a0, &out4[i0]);
    __builtin_nontemporal_store(a1, &out4[i1]);
    __builtin_nontemporal_store(v0, &out4[N4 + i0]);
    __builtin_nontemporal_store(v1, &out4[N4 + i1]);
}

extern "C" void kernel_launch(void* const* d_in, const int* in_sizes, int n_in,
                              void* d_out, int out_size, void* d_ws, size_t ws_size,
                              hipStream_t stream) {
    const f32x4* aco = (const f32x4*)d_in[0];
    const f32x4* vis = (const f32x4*)d_in[1];
    const int*   isb = (const int*)d_in[2];
    const float* Wh  = (const float*)d_in[3];
    const float* bh  = (const float*)d_in[4];
    const float* Ww  = (const float*)d_in[5];
    const float* bw  = (const float*)d_in[6];
    const float* cw  = (const float*)d_in[7];
    const float* cb  = (const float*)d_in[8];
    f32x4* out = (f32x4*)d_out;

    float* ws = (float*)d_ws;
    float* rowMean = ws;                          // BB*TT   = 8192 floats
    float* colpart = rowMean + BB * TT;           // 1024*DD = 262144 floats
    float* h_att   = colpart + 1024 * DD;         // BB*TT   = 8192 floats
    float* w_att   = h_att + BB * TT;             // BB*DD   = 32768 floats
    int*   cnt     = (int*)(w_att + (size_t)BB * DD);  // BB ints

    hipMemsetAsync(cnt, 0, BB * sizeof(int), stream);

    k_sum<<<1024, 256, 0, stream>>>(aco, vis, rowMean, colpart,
                                    h_att, w_att, Wh, bh, Ww, bw, cnt);
    k_apply<<<8192, 256, 0, stream>>>(aco, vis, isb, h_att, w_att, cw, cb, out);
}

// Round 9
// 76.885 us; speedup vs baseline: 3.0350x; 3.0350x over previous
//
#include <hip/hip_runtime.h>
#include <math.h>

// Problem constants (fixed by reference setup_inputs)
#define BB 128
#define LL 512
#define DD 256
#define TT 64
#define GG 8       // LL / TT
#define NQ (DD/4)  // 64 f32x4 per D-row

typedef float f32x4 __attribute__((ext_vector_type(4)));

__device__ __forceinline__ float sigm(float x) {
    return 1.0f / (1.0f + __expf(-x));
}
__device__ __forceinline__ f32x4 sigm4(f32x4 z) {
    f32x4 r;
    r.x = sigm(z.x); r.y = sigm(z.y); r.z = sigm(z.z); r.w = sigm(z.w);
    return r;
}

// ---------------- K1: summaries only ----------------
// grid = 1024 blocks (b, t8-chunk) x 256 threads. Wave w owns t-groups
// (t8*8 + 2w, +1), i.e. 16 rows. Emits rowMean[b,t] (hw mean over D) and
// colpart[bk,d] (hw summed over this block's 8 t-groups). No bulk writes.
__global__ __launch_bounds__(256) void k_sum(
    const f32x4* __restrict__ aco4, const f32x4* __restrict__ vis4,
    float* __restrict__ rowMean,   // [BB*TT]
    float* __restrict__ colpart)   // [1024*DD]
{
    const int tid  = threadIdx.x;
    const int w    = tid >> 6;
    const int lane = tid & 63;
    const int bk   = blockIdx.x;
    const int b    = bk >> 3;
    const int t8   = bk & 7;

    const size_t rowBase = (size_t)b * LL + (size_t)t8 * 64 + (size_t)w * 16;

    // hw = 0.5*(mean_a + mean_v) = (sum over 8 rows of (a+v)) / 16
    f32x4 hw0 = 0.f, hw1 = 0.f;
#pragma unroll
    for (int j = 0; j < 8; ++j)
        hw0 += aco4[(rowBase + j) * NQ + lane] + vis4[(rowBase + j) * NQ + lane];
#pragma unroll
    for (int j = 0; j < 8; ++j)
        hw1 += aco4[(rowBase + 8 + j) * NQ + lane] + vis4[(rowBase + 8 + j) * NQ + lane];
    hw0 *= 0.0625f;
    hw1 *= 0.0625f;

    // row means over D for the wave's two t-groups (64 lanes = 1 wave)
    float s0 = hw0.x + hw0.y + hw0.z + hw0.w;
    float s1 = hw1.x + hw1.y + hw1.z + hw1.w;
#pragma unroll
    for (int off = 32; off > 0; off >>= 1) {
        s0 += __shfl_xor(s0, off, 64);
        s1 += __shfl_xor(s1, off, 64);
    }
    if (lane == 0) {
        const int btBase = b * TT + t8 * 8 + 2 * w;
        rowMean[btBase]     = s0 * (1.0f / DD);
        rowMean[btBase + 1] = s1 * (1.0f / DD);
    }

    // per-block column partial (sum of hw over 8 t-groups, per d)
    __shared__ __align__(16) float red[4][DD];
    *reinterpret_cast<f32x4*>(&red[w][lane * 4]) = hw0 + hw1;
    __syncthreads();
    colpart[(size_t)bk * DD + tid] =
        red[0][tid] + red[1][tid] + red[2][tid] + red[3][tid];
}

// ---------------- K2: gates ----------------
// grid = BB x 256 threads. h_att = sigm(rowMean @ Wh^T + bh),
// w_att = sigm(colMean @ Ww^T + bw).
__global__ __launch_bounds__(256) void k_gates(
    const float* __restrict__ colpart, const float* __restrict__ rowMean,
    const float* __restrict__ Wh, const float* __restrict__ bh,
    const float* __restrict__ Ww, const float* __restrict__ bw,
    float* __restrict__ h_att, float* __restrict__ w_att)
{
    const int b = blockIdx.x;
    const int d = threadIdx.x;

    __shared__ float rm[TT];
    __shared__ float cm[DD];

    {
        float cs = 0.f;
#pragma unroll
        for (int p = 0; p < 8; ++p)
            cs += colpart[(size_t)(b * 8 + p) * DD + d];
        cm[d] = cs * (1.0f / TT);
        if (d < TT) rm[d] = rowMean[b * TT + d];
    }
    __syncthreads();

    if (d < TT) {
        float acc = bh[d];
#pragma unroll 8
        for (int j = 0; j < TT; ++j) acc += rm[j] * Wh[d * TT + j];
        h_att[b * TT + d] = sigm(acc);
    }
    {
        float acc = bw[d];
        const f32x4* Wr = reinterpret_cast<const f32x4*>(Ww + (size_t)d * DD);
#pragma unroll 8
        for (int kq = 0; kq < NQ; ++kq) {
            f32x4 wq = Wr[kq];
            acc += cm[4 * kq] * wq.x + cm[4 * kq + 1] * wq.y +
                   cm[4 * kq + 2] * wq.z + cm[4 * kq + 3] * wq.w;
        }
        w_att[b * DD + d] = sigm(acc);
    }
}

// ---------------- K3: pool-recompute + apply ----------------
// grid = 8192 blocks (b, t) x 256 threads (r=tid>>6 in 0..3, q=tid&63).
// Thread owns rows (t*8 + r) and (t*8 + r + 4), one f32x4 column each.
// Pools its own 8-row group in LDS (bytes already needed for apply),
// recomputes c_att locally, applies scale, NT-stores both outputs.
__global__ __launch_bounds__(256) void k_apply(
    const f32x4* __restrict__ aco4, const f32x4* __restrict__ vis4,
    const int* __restrict__ isb,
    const float* __restrict__ h_att, const float* __restrict__ w_att,
    const float* __restrict__ cw, const float* __restrict__ cb,
    f32x4* __restrict__ out4)
{
    const int tid = threadIdx.x;
    const int r   = tid >> 6;
    const int q   = tid & 63;
    const int bk  = blockIdx.x;
    const int b   = bk >> 6;
    const int t   = bk & 63;

    const size_t row0 = (size_t)b * LL + (size_t)t * GG + r;  // rows r, r+4
    const size_t N4   = (size_t)BB * LL * NQ;

    const size_t i0 = row0 * NQ + q;
    const size_t i1 = (row0 + 4) * NQ + q;

    f32x4 a0 = aco4[i0], a1 = aco4[i1];
    f32x4 v0 = vis4[i0], v1 = vis4[i1];

    __shared__ __align__(16) f32x4 redA[4][64];
    __shared__ __align__(16) f32x4 redV[4][64];
    redA[r][q] = a0 + a1;
    redV[r][q] = v0 + v1;
    __syncthreads();

    const f32x4 pa = (redA[0][q] + redA[1][q] + redA[2][q] + redA[3][q]) * 0.125f;
    const f32x4 pv = (redV[0][q] + redV[1][q] + redV[2][q] + redV[3][q]) * 0.125f;

    const f32x4 c  = sigm4(cw[0] * pa + cw[1] * pv + cb[0]);
    const float h  = h_att[b * TT + t];
    const f32x4 w4 = *reinterpret_cast<const f32x4*>(w_att + (size_t)b * DD + q * 4);
    const f32x4 sc = (h + w4 + c) * (1.0f / 3.0f);

    const int m0 = isb[row0];
    const int m1 = isb[row0 + 4];
    if (m0 == 1) { a0 *= sc; v0 *= sc; }
    if (m1 == 1) { a1 *= sc; v1 *= sc; }

    __builtin_nontemporal_store(a0, &out4[i0]);
    __builtin_nontemporal_store(a1, &out4[i1]);
    __builtin_nontemporal_store(v0, &out4[N4 + i0]);
    __builtin_nontemporal_store(v1, &out4[N4 + i1]);
}

extern "C" void kernel_launch(void* const* d_in, const int* in_sizes, int n_in,
                              void* d_out, int out_size, void* d_ws, size_t ws_size,
                              hipStream_t stream) {
    const f32x4* aco = (const f32x4*)d_in[0];
    const f32x4* vis = (const f32x4*)d_in[1];
    const int*   isb = (const int*)d_in[2];
    const float* Wh  = (const float*)d_in[3];
    const float* bh  = (const float*)d_in[4];
    const float* Ww  = (const float*)d_in[5];
    const float* bw  = (const float*)d_in[6];
    const float* cw  = (const float*)d_in[7];
    const float* cb  = (const float*)d_in[8];
    f32x4* out = (f32x4*)d_out;

    float* ws = (float*)d_ws;
    float* rowMean = ws;                          // BB*TT      = 8192 floats
    float* colpart = rowMean + BB * TT;           // 1024*DD    = 262144 floats
    float* h_att   = colpart + 1024 * DD;         // BB*TT      = 8192 floats
    float* w_att   = h_att + BB * TT;             // BB*DD      = 32768 floats

    k_sum<<<1024, 256, 0, stream>>>(aco, vis, rowMean, colpart);
    k_gates<<<BB, 256, 0, stream>>>(colpart, rowMean, Wh, bh, Ww, bw, h_att, w_att);
    k_apply<<<BB * TT, 256, 0, stream>>>(aco, vis, isb, h_att, w_att, cw, cb, out);
}